// Round 7
// baseline (517.357 us; speedup 1.0000x reference)
//
#include <hip/hip_runtime.h>

typedef __bf16 bf16x8 __attribute__((ext_vector_type(8)));
typedef float f32x4 __attribute__((ext_vector_type(4)));
typedef unsigned short u16x4 __attribute__((ext_vector_type(4)));
typedef unsigned short u16x8 __attribute__((ext_vector_type(8)));

#define NBATCH 8
#define LPTS   16384
#define CDIM   256
#define KANC   64
#define DIN    512
#define H1DIM  128
#define H2DIM  256
#define TM     64

__device__ __forceinline__ unsigned short f2b(float f){
  __bf16 h = (__bf16)f;                 // native v_cvt, RNE
  return __builtin_bit_cast(unsigned short, h);
}

// Barrier WITHOUT vmcnt drain: flush this wave's LDS ops, rendezvous, fence
// the compiler. Outstanding global loads (prefetch) stay in flight.
#define LBAR() do{ \
  asm volatile("s_waitcnt lgkmcnt(0)" ::: "memory"); \
  __builtin_amdgcn_s_barrier(); \
  asm volatile("" ::: "memory"); \
} while(0)

// wt[0..65536) = W1T[128][512]; wt[65536..98304) = W2T[256][128];
// wt[98304..163840) = W3T[256][256]   (all bf16)
__global__ __launch_bounds__(256) void prep_weights(
    const float* __restrict__ W1, const float* __restrict__ W2,
    const float* __restrict__ W3, unsigned short* __restrict__ wt){
  int id = blockIdx.x * 256 + threadIdx.x;
  if (id < 65536){
    int r = id >> 9, c = id & 511;
    wt[id] = f2b(W1[c * 128 + r]);
  } else if (id < 98304){
    int t = id - 65536; int r = t >> 7, c = t & 127;
    wt[id] = f2b(W2[c * 256 + r]);
  } else if (id < 163840){
    int t = id - 98304; int r = t >> 8, c = t & 255;
    wt[id] = f2b(W3[c * 256 + r]);
  }
}

// Persistent: 512 blocks (2/CU), each processes 8 consecutive tiles of one
// (strm, n). LDS 80 KiB. Cross-tile reg prefetch survives LBAR barriers.
__global__ __launch_bounds__(512, 4) void fused(
    const float* __restrict__ feat0, const float* __restrict__ feat1,
    const float* __restrict__ pts0, const float* __restrict__ pts1,
    const int* __restrict__ anc_i, const int* __restrict__ anc_j,
    const float* __restrict__ b1, const float* __restrict__ b2,
    const float* __restrict__ b3, const unsigned short* __restrict__ wt,
    float* __restrict__ out)
{
  __shared__ unsigned short xs[TM * DIN];     // 64 KiB
  __shared__ unsigned short h1s[TM * H1DIM];  // 16 KiB
  unsigned short* h2s = xs;                   // xs dead (as input) after G1
  float4* anc4 = (float4*)h1s;                // stride-9 padded; reloaded/tile

  const int tid  = threadIdx.x;
  const int b    = blockIdx.x;        // 0..511
  const int strm = b >> 8;
  const int n    = (b >> 5) & 7;
  const int tb   = b & 31;            // tiles tb*8 .. tb*8+7 (same strm,n)

  const float* feat = strm ? feat1 : feat0;
  const float* pts  = strm ? pts1 : pts0;
  const int*   anci = strm ? anc_j : anc_i;

  const int lane = tid & 63;
  const int w    = tid >> 6;
  const int lr   = lane & 15, lg = lane >> 4;

  // ---- per-block hoisted GEMM constants ----
  const int col1 = w * 16 + lr;
  const unsigned short* wrow1 = wt + col1 * DIN;
  const float bias1v = b1[col1];
  const int col23 = w * 32;
  const float bias2v0 = b2[col23 + lr], bias2v1 = b2[col23 + 16 + lr];
  const float bias3v0 = b3[col23 + lr], bias3v1 = b3[col23 + 16 + lr];
  const unsigned short* w2t = wt + 65536;
  const unsigned short* w3t = wt + 98304;

  const size_t fB = (size_t)n * LPTS;

  // ---- anchors (tile-invariant; clobbered by h1s, re-gathered per tile)
  if (tid < KANC){
    int ai = anci[n * KANC + tid];
    const float* ap = pts + (fB + ai) * 3;
    anc4[tid + (tid >> 3)] = make_float4(ap[0], ap[1], ap[2], 0.f);
  }

  // ---- prefetch tile 0 (feat -> regs, pts -> regs)
  float4 fv[8];
  {
    const float4* fb = (const float4*)(feat + (fB + tb * 512) * CDIM);
    #pragma unroll
    for (int it = 0; it < 8; ++it) fv[it] = fb[it * 512 + tid];
  }
  float px, py, pz;
  {
    const float* pp = pts + (fB + tb * 512 + (tid >> 3)) * 3;
    px = pp[0]; py = pp[1]; pz = pp[2];
  }
  __syncthreads();

  #pragma unroll 1
  for (int i = 0; i < 8; ++i){
    const int l0i = tb * 512 + i * 64;

    // ---- Phase A': fv regs -> xs[:,0:256)
    #pragma unroll
    for (int it = 0; it < 8; ++it){
      int flat = it * 512 + tid;
      int r = flat >> 6, c4 = flat & 63;
      float4 v = fv[it];
      int e = (r * DIN + c4 * 4) ^ ((r & 7) << 3);
      u16x4 pk = { f2b(v.x), f2b(v.y), f2b(v.z), f2b(v.w) };
      *(u16x4*)&xs[e] = pk;
    }

    // ---- Phase B: structured features -> xs[:,256:512)
    {
      const int l = tid >> 3, sub = tid & 7;
      float s0 = 0.f, s1 = 0.f, s2 = 0.f, s3 = 0.f;
      #pragma unroll
      for (int k = 0; k < 8; ++k){
        float4 a = anc4[sub * 9 + k];
        float dx = px - a.x, dy = py - a.y, dz = pz - a.z;
        float d2 = dx*dx + dy*dy + dz*dz;
        s0 += fabsf(dx); s1 += fabsf(dy); s2 += fabsf(dz); s3 += d2;
      }
      #pragma unroll
      for (int m = 1; m <= 4; m <<= 1){
        s0 += __shfl_xor(s0, m, 64);
        s1 += __shfl_xor(s1, m, 64);
        s2 += __shfl_xor(s2, m, 64);
        s3 += __shfl_xor(s3, m, 64);
      }
      float i0 = 1.f/s0, i1 = 1.f/s1, i2 = 1.f/s2, i3 = 1.f/s3;

      u16x8 o0, o1, o2, o3;
      #pragma unroll
      for (int k = 0; k < 8; ++k){
        float4 a = anc4[sub * 9 + k];
        float dx = px - a.x, dy = py - a.y, dz = pz - a.z;
        float d2 = dx*dx + dy*dy + dz*dz;
        o0[k] = f2b(dx * i0); o1[k] = f2b(dy * i1);
        o2[k] = f2b(dz * i2); o3[k] = f2b(d2 * i3);
      }
      int base = l * DIN + 256 + sub * 8;
      int swl = (l & 7) << 3;
      *(u16x8*)&xs[(base      ) ^ swl] = o0;
      *(u16x8*)&xs[(base +  64) ^ swl] = o1;
      *(u16x8*)&xs[(base + 128) ^ swl] = o2;
      *(u16x8*)&xs[(base + 192) ^ swl] = o3;
    }

    // ---- issue next-tile prefetch (in flight across all GEMM barriers)
    if (i < 7){
      const float4* fbn = (const float4*)(feat + (fB + l0i + 64) * CDIM);
      #pragma unroll
      for (int it = 0; it < 8; ++it) fv[it] = fbn[it * 512 + tid];
      const float* ppn = pts + (fB + l0i + 64 + (tid >> 3)) * 3;
      px = ppn[0]; py = ppn[1]; pz = ppn[2];
    }
    LBAR();   // xs ready

    // ---- GEMM1: xs[64,512] @ W1 -> relu -> h1s[64,128]
    {
      f32x4 acc[4] = {};
      #pragma unroll 4
      for (int kk = 0; kk < 16; ++kk){
        int kb = kk * 32 + lg * 8;
        bf16x8 bfr = *(const bf16x8*)&wrow1[kb];
        #pragma unroll
        for (int m = 0; m < 4; ++m){
          int row = m * 16 + lr;
          bf16x8 a = *(const bf16x8*)&xs[(row * DIN + kb) ^ ((row & 7) << 3)];
          acc[m] = __builtin_amdgcn_mfma_f32_16x16x32_bf16(a, bfr, acc[m], 0, 0, 0);
        }
      }
      #pragma unroll
      for (int m = 0; m < 4; ++m){
        #pragma unroll
        for (int r = 0; r < 4; ++r){
          int row = m * 16 + lg * 4 + r;
          float v = fmaxf(acc[m][r] + bias1v, 0.f);
          h1s[(row * H1DIM + col1) ^ ((row & 7) << 3)] = f2b(v);
        }
      }
    }
    LBAR();   // h1s ready (and G1's xs reads retired)

    // ---- GEMM2: h1s[64,128] @ W2 -> relu -> h2s[64,256]
    {
      f32x4 acc[4][2] = {};
      #pragma unroll
      for (int kk = 0; kk < 4; ++kk){
        int kb = kk * 32 + lg * 8;
        bf16x8 bf0 = *(const bf16x8*)&w2t[(col23 + lr) * H1DIM + kb];
        bf16x8 bf1 = *(const bf16x8*)&w2t[(col23 + 16 + lr) * H1DIM + kb];
        #pragma unroll
        for (int m = 0; m < 4; ++m){
          int row = m * 16 + lr;
          bf16x8 a = *(const bf16x8*)&h1s[(row * H1DIM + kb) ^ ((row & 7) << 3)];
          acc[m][0] = __builtin_amdgcn_mfma_f32_16x16x32_bf16(a, bf0, acc[m][0], 0, 0, 0);
          acc[m][1] = __builtin_amdgcn_mfma_f32_16x16x32_bf16(a, bf1, acc[m][1], 0, 0, 0);
        }
      }
      LBAR();   // all h1s reads retired before h2s(=xs) writes
      #pragma unroll
      for (int nt = 0; nt < 2; ++nt){
        float bias = nt ? bias2v1 : bias2v0;
        int col = col23 + nt * 16 + lr;
        #pragma unroll
        for (int m = 0; m < 4; ++m){
          #pragma unroll
          for (int r = 0; r < 4; ++r){
            int row = m * 16 + lg * 4 + r;
            float v = fmaxf(acc[m][nt][r] + bias, 0.f);
            h2s[(row * H2DIM + col) ^ ((row & 7) << 3)] = f2b(v);
          }
        }
      }
    }
    LBAR();   // h2s ready

    // ---- GEMM3: h2s[64,256] @ W3 -> + b3 -> out; anchor re-gather rides along
    {
      if (i < 7 && tid < KANC){
        int ai = anci[n * KANC + tid];                 // L1/L2-hot
        const float* ap = pts + (fB + ai) * 3;
        anc4[tid + (tid >> 3)] = make_float4(ap[0], ap[1], ap[2], 0.f);
      }
      f32x4 acc[4][2] = {};
      #pragma unroll 4
      for (int kk = 0; kk < 8; ++kk){
        int kb = kk * 32 + lg * 8;
        bf16x8 bf0 = *(const bf16x8*)&w3t[(col23 + lr) * H2DIM + kb];
        bf16x8 bf1 = *(const bf16x8*)&w3t[(col23 + 16 + lr) * H2DIM + kb];
        #pragma unroll
        for (int m = 0; m < 4; ++m){
          int row = m * 16 + lr;
          bf16x8 a = *(const bf16x8*)&h2s[(row * H2DIM + kb) ^ ((row & 7) << 3)];
          acc[m][0] = __builtin_amdgcn_mfma_f32_16x16x32_bf16(a, bf0, acc[m][0], 0, 0, 0);
          acc[m][1] = __builtin_amdgcn_mfma_f32_16x16x32_bf16(a, bf1, acc[m][1], 0, 0, 0);
        }
      }
      float* ob = out + (((size_t)strm * NBATCH + n) * LPTS + l0i) * CDIM;
      #pragma unroll
      for (int nt = 0; nt < 2; ++nt){
        float bias = nt ? bias3v1 : bias3v0;
        int col = col23 + nt * 16 + lr;
        #pragma unroll
        for (int m = 0; m < 4; ++m){
          #pragma unroll
          for (int r = 0; r < 4; ++r){
            int row = m * 16 + lg * 4 + r;
            ob[(size_t)row * CDIM + col] = acc[m][nt][r] + bias;
          }
        }
      }
    }
    LBAR();   // G3's xs reads retired; anc4 visible for next Phase B
  }
}

extern "C" void kernel_launch(void* const* d_in, const int* in_sizes, int n_in,
                              void* d_out, int out_size, void* d_ws, size_t ws_size,
                              hipStream_t stream){
  const float* feat0 = (const float*)d_in[0];
  const float* feat1 = (const float*)d_in[1];
  const float* pts0  = (const float*)d_in[2];
  const float* pts1  = (const float*)d_in[3];
  const int*   anci  = (const int*)d_in[4];
  const int*   ancj  = (const int*)d_in[5];
  const float* W1    = (const float*)d_in[6];
  const float* b1    = (const float*)d_in[7];
  const float* W2    = (const float*)d_in[8];
  const float* b2    = (const float*)d_in[9];
  const float* W3    = (const float*)d_in[10];
  const float* b3    = (const float*)d_in[11];
  unsigned short* wt = (unsigned short*)d_ws;
  float* out = (float*)d_out;

  prep_weights<<<640, 256, 0, stream>>>(W1, W2, W3, wt);
  fused<<<512, 512, 0, stream>>>(feat0, feat1, pts0, pts1, anci, ancj,
                                 b1, b2, b3, wt, out);
}

// Round 8
// 379.673 us; speedup vs baseline: 1.3626x; 1.3626x over previous
//
#include <hip/hip_runtime.h>

typedef __bf16 bf16x8 __attribute__((ext_vector_type(8)));
typedef float f32x4 __attribute__((ext_vector_type(4)));
typedef unsigned short u16x8 __attribute__((ext_vector_type(8)));

#define NBATCH 8
#define LPTS   16384
#define CDIM   256
#define KANC   64
#define DIN    512
#define H1DIM  128
#define H2DIM  256
#define TM     64

__device__ __forceinline__ unsigned short f2b(float f){
  __bf16 h = (__bf16)f;                 // native v_cvt, RNE
  return __builtin_bit_cast(unsigned short, h);
}

__device__ __forceinline__ bf16x8 cvt8(float4 a, float4 b){
  bf16x8 r;
  r[0]=(__bf16)a.x; r[1]=(__bf16)a.y; r[2]=(__bf16)a.z; r[3]=(__bf16)a.w;
  r[4]=(__bf16)b.x; r[5]=(__bf16)b.y; r[6]=(__bf16)b.z; r[7]=(__bf16)b.w;
  return r;
}

// wt[0..65536) = W1T[128][512]; wt[65536..98304) = W2T[256][128];
// wt[98304..163840) = W3T[256][256]   (all bf16)
__global__ __launch_bounds__(256) void prep_weights(
    const float* __restrict__ W1, const float* __restrict__ W2,
    const float* __restrict__ W3, unsigned short* __restrict__ wt){
  int id = blockIdx.x * 256 + threadIdx.x;
  if (id < 65536){
    int r = id >> 9, c = id & 511;
    wt[id] = f2b(W1[c * 128 + r]);
  } else if (id < 98304){
    int t = id - 65536; int r = t >> 7, c = t & 127;
    wt[id] = f2b(W2[c * 256 + r]);
  } else if (id < 163840){
    int t = id - 98304; int r = t >> 8, c = t & 255;
    wt[id] = f2b(W3[c * 256 + r]);
  }
}

// TM=64, 512 threads (8 waves). LDS 48 KiB -> 3 blocks/CU (24 waves/CU).
// feat half of GEMM1 is read directly from global (no Phase A staging).
__global__ __launch_bounds__(512, 6) void fused(
    const float* __restrict__ feat0, const float* __restrict__ feat1,
    const float* __restrict__ pts0, const float* __restrict__ pts1,
    const int* __restrict__ anc_i, const int* __restrict__ anc_j,
    const float* __restrict__ b1, const float* __restrict__ b2,
    const float* __restrict__ b3, const unsigned short* __restrict__ wt,
    float* __restrict__ out)
{
  __shared__ unsigned short xs[TM * 256];     // 32 KiB: S-features [64][256]
  __shared__ unsigned short h1s[TM * H1DIM];  // 16 KiB
  unsigned short* h2s = xs;                   // [64][256] bf16, aliases xs
  float4* anc4 = (float4*)h1s;                // stride-9 padded: 72 float4

  const int tid  = threadIdx.x;
  const int wg   = blockIdx.x;
  const int strm = wg >> 11;
  const int n    = (wg >> 8) & 7;
  const int l0   = (wg & 255) * TM;

  const float* feat = strm ? feat1 : feat0;
  const float* pts  = strm ? pts1 : pts0;
  const int*   anci = strm ? anc_j : anc_i;

  const size_t fB = (size_t)n * LPTS;

  // hoisted pts load for Phase B (latency hides under anchor gather)
  const float* pp = pts + (fB + l0 + (tid >> 3)) * 3;
  float px = pp[0], py = pp[1], pz = pp[2];

  // anchors -> LDS (stride-9 padded float4: conflict-free)
  if (tid < KANC){
    int ai = anci[n * KANC + tid];
    const float* ap = pts + (fB + ai) * 3;
    anc4[tid + (tid >> 3)] = make_float4(ap[0], ap[1], ap[2], 0.f);
  }
  __syncthreads();                            // bar1: anchors ready

  // ---- Phase B: structured features -> xs[64][256]
  // 8 threads/point, 8 anchors each, shfl_xor L1 reduce.
  {
    const int l   = tid >> 3;                 // 0..63
    const int sub = tid & 7;
    float s0 = 0.f, s1 = 0.f, s2 = 0.f, s3 = 0.f;
    #pragma unroll
    for (int i = 0; i < 8; ++i){
      float4 a = anc4[sub * 9 + i];
      float dx = px - a.x, dy = py - a.y, dz = pz - a.z;
      float d2 = dx*dx + dy*dy + dz*dz;
      s0 += fabsf(dx); s1 += fabsf(dy); s2 += fabsf(dz); s3 += d2;
    }
    #pragma unroll
    for (int m = 1; m <= 4; m <<= 1){
      s0 += __shfl_xor(s0, m, 64);
      s1 += __shfl_xor(s1, m, 64);
      s2 += __shfl_xor(s2, m, 64);
      s3 += __shfl_xor(s3, m, 64);
    }
    float i0 = 1.f/s0, i1 = 1.f/s1, i2 = 1.f/s2, i3 = 1.f/s3;

    u16x8 o0, o1, o2, o3;
    #pragma unroll
    for (int i = 0; i < 8; ++i){
      float4 a = anc4[sub * 9 + i];
      float dx = px - a.x, dy = py - a.y, dz = pz - a.z;
      float d2 = dx*dx + dy*dy + dz*dz;
      o0[i] = f2b(dx * i0); o1[i] = f2b(dy * i1);
      o2[i] = f2b(dz * i2); o3[i] = f2b(d2 * i3);
    }
    int base = l * 256 + sub * 8;
    int swl = (l & 7) << 3;
    *(u16x8*)&xs[(base      ) ^ swl] = o0;
    *(u16x8*)&xs[(base +  64) ^ swl] = o1;
    *(u16x8*)&xs[(base + 128) ^ swl] = o2;
    *(u16x8*)&xs[(base + 192) ^ swl] = o3;
  }
  __syncthreads();                            // bar2: xs ready

  const int lane = tid & 63;
  const int w    = tid >> 6;
  const int lr   = lane & 15, lg = lane >> 4;

  // ---- GEMM1 (2M x 4N wave grid): [F | S] @ W1 -> relu -> h1s[64,128]
  {
    const int wr = w >> 2, wc = w & 3;
    f32x4 acc[2][2] = {};
    const float* f0 = feat + (fB + l0 + wr * 32 + lr) * (size_t)CDIM;
    const float* f1 = f0 + 16 * (size_t)CDIM;
    const unsigned short* bq0 = wt + (wc * 32      + lr) * DIN;
    const unsigned short* bq1 = wt + (wc * 32 + 16 + lr) * DIN;

    // F-part: K = 0..256, A built from global feat (cvt f32->bf16 in regs)
    #pragma unroll
    for (int kk = 0; kk < 8; ++kk){
      int kf = kk * 32 + lg * 8;
      bf16x8 b0  = *(const bf16x8*)&bq0[kf];
      bf16x8 b1v = *(const bf16x8*)&bq1[kf];
      float4 lo0 = *(const float4*)&f0[kf], hi0 = *(const float4*)&f0[kf + 4];
      float4 lo1 = *(const float4*)&f1[kf], hi1 = *(const float4*)&f1[kf + 4];
      bf16x8 a0 = cvt8(lo0, hi0), a1 = cvt8(lo1, hi1);
      acc[0][0] = __builtin_amdgcn_mfma_f32_16x16x32_bf16(a0, b0,  acc[0][0], 0, 0, 0);
      acc[0][1] = __builtin_amdgcn_mfma_f32_16x16x32_bf16(a0, b1v, acc[0][1], 0, 0, 0);
      acc[1][0] = __builtin_amdgcn_mfma_f32_16x16x32_bf16(a1, b0,  acc[1][0], 0, 0, 0);
      acc[1][1] = __builtin_amdgcn_mfma_f32_16x16x32_bf16(a1, b1v, acc[1][1], 0, 0, 0);
    }
    // S-part: K = 256..512, A from LDS xs
    const int row0 = wr * 32 + lr, row1 = row0 + 16;
    #pragma unroll
    for (int kk = 0; kk < 8; ++kk){
      int ks = kk * 32 + lg * 8;
      bf16x8 b0  = *(const bf16x8*)&bq0[256 + ks];
      bf16x8 b1v = *(const bf16x8*)&bq1[256 + ks];
      bf16x8 a0 = *(const bf16x8*)&xs[(row0 * 256 + ks) ^ ((row0 & 7) << 3)];
      bf16x8 a1 = *(const bf16x8*)&xs[(row1 * 256 + ks) ^ ((row1 & 7) << 3)];
      acc[0][0] = __builtin_amdgcn_mfma_f32_16x16x32_bf16(a0, b0,  acc[0][0], 0, 0, 0);
      acc[0][1] = __builtin_amdgcn_mfma_f32_16x16x32_bf16(a0, b1v, acc[0][1], 0, 0, 0);
      acc[1][0] = __builtin_amdgcn_mfma_f32_16x16x32_bf16(a1, b0,  acc[1][0], 0, 0, 0);
      acc[1][1] = __builtin_amdgcn_mfma_f32_16x16x32_bf16(a1, b1v, acc[1][1], 0, 0, 0);
    }
    #pragma unroll
    for (int nn = 0; nn < 2; ++nn){
      int col = wc * 32 + nn * 16 + lr;
      float bias = b1[col];
      #pragma unroll
      for (int m = 0; m < 2; ++m){
        #pragma unroll
        for (int r = 0; r < 4; ++r){
          int row = wr * 32 + m * 16 + lg * 4 + r;
          float v = fmaxf(acc[m][nn][r] + bias, 0.f);
          h1s[(row * H1DIM + col) ^ ((row & 7) << 3)] = f2b(v);
        }
      }
    }
  }
  __syncthreads();                            // bar3: h1s ready, xs reads retired

  // ---- GEMM2: h1s[64,128] @ W2 -> relu -> h2s[64,256] (aliases xs; safe:
  // all xs reads retired at bar3; h1s and h2s are disjoint buffers)
  {
    const unsigned short* w2t = wt + 65536;
    f32x4 acc[4][2] = {};
    const int col0 = w * 32;
    #pragma unroll
    for (int kk = 0; kk < 4; ++kk){
      int kb = kk * 32 + lg * 8;
      bf16x8 bf0 = *(const bf16x8*)&w2t[(col0 + lr) * H1DIM + kb];
      bf16x8 bf1 = *(const bf16x8*)&w2t[(col0 + 16 + lr) * H1DIM + kb];
      #pragma unroll
      for (int m = 0; m < 4; ++m){
        int row = m * 16 + lr;
        bf16x8 a = *(const bf16x8*)&h1s[(row * H1DIM + kb) ^ ((row & 7) << 3)];
        acc[m][0] = __builtin_amdgcn_mfma_f32_16x16x32_bf16(a, bf0, acc[m][0], 0, 0, 0);
        acc[m][1] = __builtin_amdgcn_mfma_f32_16x16x32_bf16(a, bf1, acc[m][1], 0, 0, 0);
      }
    }
    #pragma unroll
    for (int nt = 0; nt < 2; ++nt){
      int col = col0 + nt * 16 + lr;
      float bias = b2[col];
      #pragma unroll
      for (int m = 0; m < 4; ++m){
        #pragma unroll
        for (int r = 0; r < 4; ++r){
          int row = m * 16 + lg * 4 + r;
          float v = fmaxf(acc[m][nt][r] + bias, 0.f);
          h2s[(row * H2DIM + col) ^ ((row & 7) << 3)] = f2b(v);
        }
      }
    }
  }
  __syncthreads();                            // bar4: h2s ready

  // ---- GEMM3: h2s[64,256] @ W3 -> + b3 -> out (f32)
  {
    const unsigned short* w3t = wt + 98304;
    f32x4 acc[4][2] = {};
    const int col0 = w * 32;
    #pragma unroll 4
    for (int kk = 0; kk < 8; ++kk){
      int kb = kk * 32 + lg * 8;
      bf16x8 bf0 = *(const bf16x8*)&w3t[(col0 + lr) * H2DIM + kb];
      bf16x8 bf1 = *(const bf16x8*)&w3t[(col0 + 16 + lr) * H2DIM + kb];
      #pragma unroll
      for (int m = 0; m < 4; ++m){
        int row = m * 16 + lr;
        bf16x8 a = *(const bf16x8*)&h2s[(row * H2DIM + kb) ^ ((row & 7) << 3)];
        acc[m][0] = __builtin_amdgcn_mfma_f32_16x16x32_bf16(a, bf0, acc[m][0], 0, 0, 0);
        acc[m][1] = __builtin_amdgcn_mfma_f32_16x16x32_bf16(a, bf1, acc[m][1], 0, 0, 0);
      }
    }
    float* ob = out + (((size_t)strm * NBATCH + n) * LPTS + l0) * CDIM;
    #pragma unroll
    for (int nt = 0; nt < 2; ++nt){
      int col = col0 + nt * 16 + lr;
      float bias = b3[col];
      #pragma unroll
      for (int m = 0; m < 4; ++m){
        #pragma unroll
        for (int r = 0; r < 4; ++r){
          int row = m * 16 + lg * 4 + r;
          ob[(size_t)row * CDIM + col] = acc[m][nt][r] + bias;
        }
      }
    }
  }
}

extern "C" void kernel_launch(void* const* d_in, const int* in_sizes, int n_in,
                              void* d_out, int out_size, void* d_ws, size_t ws_size,
                              hipStream_t stream){
  const float* feat0 = (const float*)d_in[0];
  const float* feat1 = (const float*)d_in[1];
  const float* pts0  = (const float*)d_in[2];
  const float* pts1  = (const float*)d_in[3];
  const int*   anci  = (const int*)d_in[4];
  const int*   ancj  = (const int*)d_in[5];
  const float* W1    = (const float*)d_in[6];
  const float* b1    = (const float*)d_in[7];
  const float* W2    = (const float*)d_in[8];
  const float* b2    = (const float*)d_in[9];
  const float* W3    = (const float*)d_in[10];
  const float* b3    = (const float*)d_in[11];
  unsigned short* wt = (unsigned short*)d_ws;
  float* out = (float*)d_out;

  prep_weights<<<640, 256, 0, stream>>>(W1, W2, W3, wt);
  fused<<<4096, 512, 0, stream>>>(feat0, feat1, pts0, pts1, anci, ancj,
                                  b1, b2, b3, wt, out);
}

// Round 9
// 356.359 us; speedup vs baseline: 1.4518x; 1.0654x over previous
//
#include <hip/hip_runtime.h>

typedef __bf16 bf16x8 __attribute__((ext_vector_type(8)));
typedef float f32x4 __attribute__((ext_vector_type(4)));
typedef unsigned short u16x4 __attribute__((ext_vector_type(4)));
typedef unsigned short u16x8 __attribute__((ext_vector_type(8)));

#define NBATCH 8
#define LPTS   16384
#define CDIM   256
#define KANC   64
#define DIN    512
#define H1DIM  128
#define H2DIM  256
#define TM     64

__device__ __forceinline__ unsigned short f2b(float f){
  __bf16 h = (__bf16)f;                 // native v_cvt, RNE
  return __builtin_bit_cast(unsigned short, h);
}

// wt[0..65536) = W1T[128][512]; wt[65536..98304) = W2T[256][128];
// wt[98304..163840) = W3T[256][256]   (all bf16)
__global__ __launch_bounds__(256) void prep_weights(
    const float* __restrict__ W1, const float* __restrict__ W2,
    const float* __restrict__ W3, unsigned short* __restrict__ wt){
  int id = blockIdx.x * 256 + threadIdx.x;
  if (id < 65536){
    int r = id >> 9, c = id & 511;
    wt[id] = f2b(W1[c * 128 + r]);
  } else if (id < 98304){
    int t = id - 65536; int r = t >> 7, c = t & 127;
    wt[id] = f2b(W2[c * 256 + r]);
  } else if (id < 163840){
    int t = id - 98304; int r = t >> 8, c = t & 255;
    wt[id] = f2b(W3[c * 256 + r]);
  }
}

__global__ __launch_bounds__(512, 4) void fused(
    const float* __restrict__ feat0, const float* __restrict__ feat1,
    const float* __restrict__ pts0, const float* __restrict__ pts1,
    const int* __restrict__ anc_i, const int* __restrict__ anc_j,
    const float* __restrict__ b1, const float* __restrict__ b2,
    const float* __restrict__ b3, const unsigned short* __restrict__ wt,
    float* __restrict__ out)
{
  // 80 KiB total -> 2 blocks/CU. h2 aliases xs; anc4 aliases h1s.
  __shared__ unsigned short xs[TM * DIN];     // 64 KiB
  __shared__ unsigned short h1s[TM * H1DIM];  // 16 KiB
  unsigned short* h2s = xs;
  float4* anc4 = (float4*)h1s;                // stride-9 padded: 72 float4

  const int tid  = threadIdx.x;
  const int wg   = blockIdx.x;
  const int strm = wg >> 11;
  const int n    = (wg >> 8) & 7;
  const int l0   = (wg & 255) * TM;

  const float* feat = strm ? feat1 : feat0;
  const float* pts  = strm ? pts1 : pts0;
  const int*   anci = strm ? anc_j : anc_i;

  // hoisted pts load for Phase B (latency hides under Phase A)
  const float* pp = pts + ((size_t)n * LPTS + l0 + (tid >> 3)) * 3;
  float px = pp[0], py = pp[1], pz = pp[2];

  // anchors -> LDS (stride-9 padded float4: conflict-free)
  if (tid < KANC){
    int ai = anci[n * KANC + tid];
    const float* ap = pts + ((size_t)n * LPTS + ai) * 3;
    anc4[tid + (tid >> 3)] = make_float4(ap[0], ap[1], ap[2], 0.f);
  }

  // ---- Phase A: feat tile -> xs[:, 0:256) (bf16, swizzled) — R4 verbatim
  {
    const float4* fb = (const float4*)(feat + ((size_t)n * LPTS + l0) * CDIM);
    #pragma unroll
    for (int it = 0; it < 8; ++it){
      int flat = it * 512 + tid;          // 4096 float4 in tile, 16B/lane coalesced
      int r = flat >> 6, c4 = flat & 63;
      float4 v = fb[flat];
      int e = (r * DIN + c4 * 4) ^ ((r & 7) << 3);
      u16x4 pk = { f2b(v.x), f2b(v.y), f2b(v.z), f2b(v.w) };
      *(u16x4*)&xs[e] = pk;
    }
  }
  __syncthreads();

  // ---- Phase B: structured features -> xs[:, 256:512) — R4 verbatim
  {
    const int l   = tid >> 3;             // 0..63
    const int sub = tid & 7;
    float s0 = 0.f, s1 = 0.f, s2 = 0.f, s3 = 0.f;
    #pragma unroll
    for (int i = 0; i < 8; ++i){
      float4 a = anc4[sub * 9 + i];
      float dx = px - a.x, dy = py - a.y, dz = pz - a.z;
      float d2 = dx*dx + dy*dy + dz*dz;
      s0 += fabsf(dx); s1 += fabsf(dy); s2 += fabsf(dz); s3 += d2;
    }
    #pragma unroll
    for (int m = 1; m <= 4; m <<= 1){
      s0 += __shfl_xor(s0, m, 64);
      s1 += __shfl_xor(s1, m, 64);
      s2 += __shfl_xor(s2, m, 64);
      s3 += __shfl_xor(s3, m, 64);
    }
    float i0 = 1.f/s0, i1 = 1.f/s1, i2 = 1.f/s2, i3 = 1.f/s3;

    u16x8 o0, o1, o2, o3;
    #pragma unroll
    for (int i = 0; i < 8; ++i){
      float4 a = anc4[sub * 9 + i];
      float dx = px - a.x, dy = py - a.y, dz = pz - a.z;
      float d2 = dx*dx + dy*dy + dz*dz;
      o0[i] = f2b(dx * i0); o1[i] = f2b(dy * i1);
      o2[i] = f2b(dz * i2); o3[i] = f2b(d2 * i3);
    }
    int base = l * DIN + 256 + sub * 8;
    int swl = (l & 7) << 3;
    *(u16x8*)&xs[(base      ) ^ swl] = o0;
    *(u16x8*)&xs[(base +  64) ^ swl] = o1;
    *(u16x8*)&xs[(base + 128) ^ swl] = o2;
    *(u16x8*)&xs[(base + 192) ^ swl] = o3;
  }
  __syncthreads();

  // ---- GEMM wave grid: 2M x 4N (halves per-wave A LDS reads vs R4)
  const int lane = tid & 63;
  const int w    = tid >> 6;
  const int wr   = w >> 2, wc = w & 3;
  const int lr   = lane & 15, lg = lane >> 4;
  const int r0   = wr * 32;
  const int sw   = (lr & 7) << 3;       // A-read swizzle (row&7 == lr&7)

  // ---- GEMM1: xs[64,512] @ W1 -> relu -> h1s[64,128]
  {
    f32x4 acc[2][2] = {};
    const unsigned short* bpA = wt + (wc * 32      + lr) * DIN;
    const unsigned short* bpB = wt + (wc * 32 + 16 + lr) * DIN;
    #pragma unroll 4
    for (int kk = 0; kk < 16; ++kk){
      int kb = kk * 32 + lg * 8;
      bf16x8 a0 = *(const bf16x8*)&xs[((r0      + lr) * DIN + kb) ^ sw];
      bf16x8 a1 = *(const bf16x8*)&xs[((r0 + 16 + lr) * DIN + kb) ^ sw];
      bf16x8 b0 = *(const bf16x8*)&bpA[kb];
      bf16x8 b1f = *(const bf16x8*)&bpB[kb];
      acc[0][0] = __builtin_amdgcn_mfma_f32_16x16x32_bf16(a0, b0,  acc[0][0], 0, 0, 0);
      acc[0][1] = __builtin_amdgcn_mfma_f32_16x16x32_bf16(a0, b1f, acc[0][1], 0, 0, 0);
      acc[1][0] = __builtin_amdgcn_mfma_f32_16x16x32_bf16(a1, b0,  acc[1][0], 0, 0, 0);
      acc[1][1] = __builtin_amdgcn_mfma_f32_16x16x32_bf16(a1, b1f, acc[1][1], 0, 0, 0);
    }
    #pragma unroll
    for (int nn = 0; nn < 2; ++nn){
      int col = wc * 32 + nn * 16 + lr;
      float bias = b1[col];
      #pragma unroll
      for (int m = 0; m < 2; ++m){
        #pragma unroll
        for (int r = 0; r < 4; ++r){
          int row = r0 + m * 16 + lg * 4 + r;
          float v = fmaxf(acc[m][nn][r] + bias, 0.f);
          h1s[(row * H1DIM + col) ^ ((row & 7) << 3)] = f2b(v);
        }
      }
    }
  }
  __syncthreads();

  // ---- GEMM2: h1s[64,128] @ W2 -> relu -> h2s[64,256]
  {
    const unsigned short* w2t = wt + 65536;
    f32x4 acc[2][4] = {};
    #pragma unroll
    for (int kk = 0; kk < 4; ++kk){
      int kb = kk * 32 + lg * 8;
      bf16x8 a0 = *(const bf16x8*)&h1s[((r0      + lr) * H1DIM + kb) ^ sw];
      bf16x8 a1 = *(const bf16x8*)&h1s[((r0 + 16 + lr) * H1DIM + kb) ^ sw];
      #pragma unroll
      for (int nn = 0; nn < 4; ++nn){
        bf16x8 b = *(const bf16x8*)&w2t[(wc * 64 + nn * 16 + lr) * H1DIM + kb];
        acc[0][nn] = __builtin_amdgcn_mfma_f32_16x16x32_bf16(a0, b, acc[0][nn], 0, 0, 0);
        acc[1][nn] = __builtin_amdgcn_mfma_f32_16x16x32_bf16(a1, b, acc[1][nn], 0, 0, 0);
      }
    }
    __syncthreads();   // all h1s reads done AND xs (GEMM1 A-reads) fully retired
    #pragma unroll
    for (int nn = 0; nn < 4; ++nn){
      int col = wc * 64 + nn * 16 + lr;
      float bias = b2[col];
      #pragma unroll
      for (int m = 0; m < 2; ++m){
        #pragma unroll
        for (int r = 0; r < 4; ++r){
          int row = r0 + m * 16 + lg * 4 + r;
          float v = fmaxf(acc[m][nn][r] + bias, 0.f);
          h2s[(row * H2DIM + col) ^ ((row & 7) << 3)] = f2b(v);
        }
      }
    }
  }
  __syncthreads();

  // ---- GEMM3: h2s[64,256] @ W3 -> + b3 -> out (f32)
  {
    const unsigned short* w3t = wt + 98304;
    f32x4 acc[2][4] = {};
    #pragma unroll 4
    for (int kk = 0; kk < 8; ++kk){
      int kb = kk * 32 + lg * 8;
      bf16x8 a0 = *(const bf16x8*)&h2s[((r0      + lr) * H2DIM + kb) ^ sw];
      bf16x8 a1 = *(const bf16x8*)&h2s[((r0 + 16 + lr) * H2DIM + kb) ^ sw];
      #pragma unroll
      for (int nn = 0; nn < 4; ++nn){
        bf16x8 b = *(const bf16x8*)&w3t[(wc * 64 + nn * 16 + lr) * H2DIM + kb];
        acc[0][nn] = __builtin_amdgcn_mfma_f32_16x16x32_bf16(a0, b, acc[0][nn], 0, 0, 0);
        acc[1][nn] = __builtin_amdgcn_mfma_f32_16x16x32_bf16(a1, b, acc[1][nn], 0, 0, 0);
      }
    }
    float* ob = out + (((size_t)strm * NBATCH + n) * LPTS + l0) * CDIM;
    #pragma unroll
    for (int nn = 0; nn < 4; ++nn){
      int col = wc * 64 + nn * 16 + lr;
      float bias = b3[nn * 16 + wc * 64 + lr];
      #pragma unroll
      for (int m = 0; m < 2; ++m){
        #pragma unroll
        for (int r = 0; r < 4; ++r){
          int row = r0 + m * 16 + lg * 4 + r;
          ob[(size_t)row * CDIM + col] = acc[m][nn][r] + bias;
        }
      }
    }
  }
}

extern "C" void kernel_launch(void* const* d_in, const int* in_sizes, int n_in,
                              void* d_out, int out_size, void* d_ws, size_t ws_size,
                              hipStream_t stream){
  const float* feat0 = (const float*)d_in[0];
  const float* feat1 = (const float*)d_in[1];
  const float* pts0  = (const float*)d_in[2];
  const float* pts1  = (const float*)d_in[3];
  const int*   anci  = (const int*)d_in[4];
  const int*   ancj  = (const int*)d_in[5];
  const float* W1    = (const float*)d_in[6];
  const float* b1    = (const float*)d_in[7];
  const float* W2    = (const float*)d_in[8];
  const float* b2    = (const float*)d_in[9];
  const float* W3    = (const float*)d_in[10];
  const float* b3    = (const float*)d_in[11];
  unsigned short* wt = (unsigned short*)d_ws;
  float* out = (float*)d_out;

  prep_weights<<<640, 256, 0, stream>>>(W1, W2, W3, wt);
  fused<<<4096, 512, 0, stream>>>(feat0, feat1, pts0, pts1, anci, ancj,
                                  b1, b2, b3, wt, out);
}

// Round 10
// 234.596 us; speedup vs baseline: 2.2053x; 1.5190x over previous
//
#include <hip/hip_runtime.h>

typedef __bf16 bf16x8 __attribute__((ext_vector_type(8)));
typedef float f32x4 __attribute__((ext_vector_type(4)));
typedef unsigned short u16x4 __attribute__((ext_vector_type(4)));

#define NBATCH 8
#define LPTS   16384
#define CDIM   256
#define KANC   64
#define DIN    512
#define H1DIM  128
#define H2DIM  256
#define TM     64

__device__ __forceinline__ unsigned short f2b(float f){
  __bf16 h = (__bf16)f;                 // native v_cvt, RNE
  return __builtin_bit_cast(unsigned short, h);
}

// wt[0..65536) = W1T[128][512]; wt[65536..98304) = W2T[256][128];
// wt[98304..163840) = W3T[256][256]   (all bf16)
__global__ __launch_bounds__(256) void prep_weights(
    const float* __restrict__ W1, const float* __restrict__ W2,
    const float* __restrict__ W3, unsigned short* __restrict__ wt){
  int id = blockIdx.x * 256 + threadIdx.x;
  if (id < 65536){
    int r = id >> 9, c = id & 511;
    wt[id] = f2b(W1[c * 128 + r]);
  } else if (id < 98304){
    int t = id - 65536; int r = t >> 7, c = t & 127;
    wt[id] = f2b(W2[c * 256 + r]);
  } else if (id < 163840){
    int t = id - 98304; int r = t >> 8, c = t & 255;
    wt[id] = f2b(W3[c * 256 + r]);
  }
}

// Rank-11 collapse of the S-half of GEMM1. coef[comb][12][128] f32:
// j: 0=SX 1=CX 2=SY 3=CY 4=SZ 5=CZ 6=SD 7=ADx 8=ADy 9=ADz 10=CD2; row 11
// cols 0..3 = SAx,SAy,SAz,SA2 (for the closed-form L1 denom of dist).
__global__ __launch_bounds__(128) void prep_coef(
    const float* __restrict__ pts0, const float* __restrict__ pts1,
    const int* __restrict__ anc_i, const int* __restrict__ anc_j,
    const float* __restrict__ W1, float* __restrict__ coef){
  const int comb = blockIdx.x;          // 0..15
  const int strm = comb >> 3, n = comb & 7;
  const int col  = threadIdx.x;         // 0..127
  __shared__ float4 anc[64];
  const float* pts  = strm ? pts1 : pts0;
  const int*   anci = strm ? anc_j : anc_i;
  if (col < 64){
    int ai = anci[n * KANC + col];
    const float* ap = pts + ((size_t)n * LPTS + ai) * 3;
    anc[col] = make_float4(ap[0], ap[1], ap[2], 0.f);
  }
  __syncthreads();
  float SX=0,CX=0,SY=0,CY=0,SZ=0,CZ=0,SD=0,ADx=0,ADy=0,ADz=0,CD2=0;
  float SAx=0,SAy=0,SAz=0,SA2=0;
  for (int k = 0; k < KANC; ++k){
    float4 a = anc[k];
    float ak2 = a.x*a.x + a.y*a.y + a.z*a.z;
    float wx = W1[(256 + k) * 128 + col];
    float wy = W1[(320 + k) * 128 + col];
    float wz = W1[(384 + k) * 128 + col];
    float wd = W1[(448 + k) * 128 + col];
    SX += wx; CX += a.x * wx;
    SY += wy; CY += a.y * wy;
    SZ += wz; CZ += a.z * wz;
    SD += wd; ADx += a.x * wd; ADy += a.y * wd; ADz += a.z * wd;
    CD2 += ak2 * wd;
    SAx += a.x; SAy += a.y; SAz += a.z; SA2 += ak2;
  }
  float* cf = coef + (size_t)comb * 12 * 128;
  cf[ 0*128+col]=SX;  cf[ 1*128+col]=CX;  cf[ 2*128+col]=SY;  cf[ 3*128+col]=CY;
  cf[ 4*128+col]=SZ;  cf[ 5*128+col]=CZ;  cf[ 6*128+col]=SD;  cf[ 7*128+col]=ADx;
  cf[ 8*128+col]=ADy; cf[ 9*128+col]=ADz; cf[10*128+col]=CD2;
  if (col == 0) cf[11*128+0] = SAx;
  if (col == 1) cf[11*128+1] = SAy;
  if (col == 2) cf[11*128+2] = SAz;
  if (col == 3) cf[11*128+3] = SA2;
}

// TM=64, 512 threads (8 waves, GEMMs 1M x 8N). LDS 51 KiB -> 3 blocks/CU.
__global__ __launch_bounds__(512, 6) void fused(
    const float* __restrict__ feat0, const float* __restrict__ feat1,
    const float* __restrict__ pts0, const float* __restrict__ pts1,
    const int* __restrict__ anc_i, const int* __restrict__ anc_j,
    const float* __restrict__ b1, const float* __restrict__ b2,
    const float* __restrict__ b3, const unsigned short* __restrict__ wt,
    const float* __restrict__ coef, float* __restrict__ out)
{
  __shared__ unsigned short xs[TM * 256];     // 32 KiB: feat tile [64][256]
  __shared__ unsigned short h1s[TM * H1DIM];  // 16 KiB
  __shared__ float scal[TM][12];              // 3 KiB: per-point u_j
  unsigned short* h2s = xs;                   // aliases xs (feat dead post-G1)
  float4* anc4 = (float4*)h1s;                // stride-9 padded, dead pre-h1s

  const int tid  = threadIdx.x;
  const int wg   = blockIdx.x;
  const int strm = wg >> 11;
  const int n    = (wg >> 8) & 7;
  const int l0   = (wg & 255) * TM;

  const float* feat = strm ? feat1 : feat0;
  const float* pts  = strm ? pts1 : pts0;
  const int*   anci = strm ? anc_j : anc_i;
  const float* cf   = coef + (size_t)((strm << 3) | n) * 12 * 128;

  // hoisted loads (latency hides under Phase A)
  const float* pp = pts + ((size_t)n * LPTS + l0 + (tid >> 3)) * 3;
  float px = pp[0], py = pp[1], pz = pp[2];
  float SAx = cf[11*128+0], SAy = cf[11*128+1], SAz = cf[11*128+2], SA2 = cf[11*128+3];

  // anchors -> LDS (stride-9 padded float4: conflict-free)
  if (tid < KANC){
    int ai = anci[n * KANC + tid];
    const float* ap = pts + ((size_t)n * LPTS + ai) * 3;
    anc4[tid + (tid >> 3)] = make_float4(ap[0], ap[1], ap[2], 0.f);
  }

  // ---- Phase A: feat tile -> xs[64][256] bf16 (coalesced, swizzled)
  {
    const float4* fb = (const float4*)(feat + ((size_t)n * LPTS + l0) * CDIM);
    #pragma unroll
    for (int it = 0; it < 8; ++it){
      int flat = it * 512 + tid;          // 4096 float4, 16B/lane coalesced
      int r = flat >> 6, c4 = flat & 63;
      float4 v = fb[flat];
      int e = (r * 256 + c4 * 4) ^ ((r & 7) << 3);
      u16x4 pk = { f2b(v.x), f2b(v.y), f2b(v.z), f2b(v.w) };
      *(u16x4*)&xs[e] = pk;
    }
  }
  __syncthreads();                        // bar1: anchors (+xs) ready

  // ---- Phase B: L1 denominators + per-point scalars -> scal[64][12]
  {
    const int l   = tid >> 3;             // 0..63
    const int sub = tid & 7;
    float s0 = 0.f, s1 = 0.f, s2 = 0.f;
    #pragma unroll
    for (int i = 0; i < 8; ++i){
      float4 a = anc4[sub * 9 + i];
      s0 += fabsf(px - a.x); s1 += fabsf(py - a.y); s2 += fabsf(pz - a.z);
    }
    #pragma unroll
    for (int m = 1; m <= 4; m <<= 1){
      s0 += __shfl_xor(s0, m, 64);
      s1 += __shfl_xor(s1, m, 64);
      s2 += __shfl_xor(s2, m, 64);
    }
    float pp2 = px*px + py*py + pz*pz;
    float s3 = 64.f * pp2 - 2.f * (px*SAx + py*SAy + pz*SAz) + SA2;
    float i0 = 1.f/s0, i1 = 1.f/s1, i2 = 1.f/s2, i3 = 1.f/s3;
    // u: 0=i0*px 1=-i0 2=i1*py 3=-i1 4=i2*pz 5=-i2 6=i3*pp2
    //    7=-2i3*px 8=-2i3*py 9=-2i3*pz 10=i3
    float u;
    switch (sub){
      case 0: u = i0 * px;       break;
      case 1: u = -i0;           break;
      case 2: u = i1 * py;       break;
      case 3: u = -i1;           break;
      case 4: u = i2 * pz;       break;
      case 5: u = -i2;           break;
      case 6: u = i3 * pp2;      break;
      default: u = -2.f*i3*px;   break;
    }
    scal[l][sub] = u;
    if (sub < 3){
      float u2 = (sub == 0) ? -2.f*i3*py : (sub == 1) ? -2.f*i3*pz : i3;
      scal[l][8 + sub] = u2;
    }
  }
  __syncthreads();                        // bar2: scal ready

  const int lane = tid & 63;
  const int w    = tid >> 6;
  const int lr   = lane & 15;
  const int lg   = lane >> 4;

  // ---- GEMM1: feat-part MFMA (K=256) + rank-11 S-part -> relu -> h1s
  {
    f32x4 acc[4] = {};
    const int col = w * 16 + lr;          // wave owns 16 cols of h1
    const unsigned short* wrow = wt + col * DIN;   // W1T row (len 512, use 0..256)
    float cc[11];
    #pragma unroll
    for (int j = 0; j < 11; ++j) cc[j] = cf[j * 128 + col];
    #pragma unroll 4
    for (int kk = 0; kk < 8; ++kk){
      int kb = kk * 32 + lg * 8;
      bf16x8 b = *(const bf16x8*)&wrow[kb];
      #pragma unroll
      for (int m = 0; m < 4; ++m){
        int row = m * 16 + lr;
        bf16x8 a = *(const bf16x8*)&xs[(row * 256 + kb) ^ ((row & 7) << 3)];
        acc[m] = __builtin_amdgcn_mfma_f32_16x16x32_bf16(a, b, acc[m], 0, 0, 0);
      }
    }
    float bias = b1[col];
    #pragma unroll
    for (int m = 0; m < 4; ++m){
      #pragma unroll
      for (int r = 0; r < 4; ++r){
        int row = m * 16 + lg * 4 + r;
        f32x4 ua = *(const f32x4*)&scal[row][0];
        f32x4 ub = *(const f32x4*)&scal[row][4];
        f32x4 uc = *(const f32x4*)&scal[row][8];
        float s = acc[m][r] + bias;
        s += ua[0]*cc[0] + ua[1]*cc[1] + ua[2]*cc[2] + ua[3]*cc[3];
        s += ub[0]*cc[4] + ub[1]*cc[5] + ub[2]*cc[6] + ub[3]*cc[7];
        s += uc[0]*cc[8] + uc[1]*cc[9] + uc[2]*cc[10];
        float v = fmaxf(s, 0.f);
        h1s[(row * H1DIM + col) ^ ((row & 7) << 3)] = f2b(v);
      }
    }
  }
  __syncthreads();                        // bar3: h1s ready, xs reads retired

  // ---- GEMM2: h1s[64,128] @ W2 -> relu -> h2s[64,256] (aliases xs)
  {
    const unsigned short* w2t = wt + 65536;
    f32x4 acc[4][2] = {};
    const int col0 = w * 32;
    #pragma unroll
    for (int kk = 0; kk < 4; ++kk){
      int kb = kk * 32 + lg * 8;
      bf16x8 bf0 = *(const bf16x8*)&w2t[(col0 + lr) * H1DIM + kb];
      bf16x8 bf1 = *(const bf16x8*)&w2t[(col0 + 16 + lr) * H1DIM + kb];
      #pragma unroll
      for (int m = 0; m < 4; ++m){
        int row = m * 16 + lr;
        bf16x8 a = *(const bf16x8*)&h1s[(row * H1DIM + kb) ^ ((row & 7) << 3)];
        acc[m][0] = __builtin_amdgcn_mfma_f32_16x16x32_bf16(a, bf0, acc[m][0], 0, 0, 0);
        acc[m][1] = __builtin_amdgcn_mfma_f32_16x16x32_bf16(a, bf1, acc[m][1], 0, 0, 0);
      }
    }
    // h2s(=xs) writes are safe: all xs reads ended before bar3; G2 reads only h1s.
    #pragma unroll
    for (int nt = 0; nt < 2; ++nt){
      int col = col0 + nt * 16 + lr;
      float bias = b2[col];
      #pragma unroll
      for (int m = 0; m < 4; ++m){
        #pragma unroll
        for (int r = 0; r < 4; ++r){
          int row = m * 16 + lg * 4 + r;
          float v = fmaxf(acc[m][nt][r] + bias, 0.f);
          h2s[(row * H2DIM + col) ^ ((row & 7) << 3)] = f2b(v);
        }
      }
    }
  }
  __syncthreads();                        // bar4: h2s ready

  // ---- GEMM3: h2s[64,256] @ W3 -> + b3 -> out (f32)
  {
    const unsigned short* w3t = wt + 98304;
    f32x4 acc[4][2] = {};
    const int col0 = w * 32;
    #pragma unroll 4
    for (int kk = 0; kk < 8; ++kk){
      int kb = kk * 32 + lg * 8;
      bf16x8 bf0 = *(const bf16x8*)&w3t[(col0 + lr) * H2DIM + kb];
      bf16x8 bf1 = *(const bf16x8*)&w3t[(col0 + 16 + lr) * H2DIM + kb];
      #pragma unroll
      for (int m = 0; m < 4; ++m){
        int row = m * 16 + lr;
        bf16x8 a = *(const bf16x8*)&h2s[(row * H2DIM + kb) ^ ((row & 7) << 3)];
        acc[m][0] = __builtin_amdgcn_mfma_f32_16x16x32_bf16(a, bf0, acc[m][0], 0, 0, 0);
        acc[m][1] = __builtin_amdgcn_mfma_f32_16x16x32_bf16(a, bf1, acc[m][1], 0, 0, 0);
      }
    }
    float* ob = out + (((size_t)strm * NBATCH + n) * LPTS + l0) * CDIM;
    #pragma unroll
    for (int nt = 0; nt < 2; ++nt){
      int col = col0 + nt * 16 + lr;
      float bias = b3[col];
      #pragma unroll
      for (int m = 0; m < 4; ++m){
        #pragma unroll
        for (int r = 0; r < 4; ++r){
          int row = m * 16 + lg * 4 + r;
          ob[(size_t)row * CDIM + col] = acc[m][nt][r] + bias;
        }
      }
    }
  }
}

extern "C" void kernel_launch(void* const* d_in, const int* in_sizes, int n_in,
                              void* d_out, int out_size, void* d_ws, size_t ws_size,
                              hipStream_t stream){
  const float* feat0 = (const float*)d_in[0];
  const float* feat1 = (const float*)d_in[1];
  const float* pts0  = (const float*)d_in[2];
  const float* pts1  = (const float*)d_in[3];
  const int*   anci  = (const int*)d_in[4];
  const int*   ancj  = (const int*)d_in[5];
  const float* W1    = (const float*)d_in[6];
  const float* b1    = (const float*)d_in[7];
  const float* W2    = (const float*)d_in[8];
  const float* b2    = (const float*)d_in[9];
  const float* W3    = (const float*)d_in[10];
  const float* b3    = (const float*)d_in[11];
  unsigned short* wt = (unsigned short*)d_ws;
  float* coef = (float*)((char*)d_ws + 163840 * sizeof(unsigned short));
  float* out = (float*)d_out;

  prep_weights<<<640, 256, 0, stream>>>(W1, W2, W3, wt);
  prep_coef<<<16, 128, 0, stream>>>(pts0, pts1, anci, ancj, W1, coef);
  fused<<<4096, 512, 0, stream>>>(feat0, feat1, pts0, pts1, anci, ancj,
                                  b1, b2, b3, wt, coef, out);
}

// Round 11
// 210.583 us; speedup vs baseline: 2.4568x; 1.1140x over previous
//
#include <hip/hip_runtime.h>

typedef __bf16 bf16x8 __attribute__((ext_vector_type(8)));
typedef float f32x4 __attribute__((ext_vector_type(4)));
typedef unsigned short u16x4 __attribute__((ext_vector_type(4)));

#define NBATCH 8
#define LPTS   16384
#define CDIM   256
#define KANC   64
#define DIN    512
#define H1DIM  128
#define H2DIM  256
#define TM     64

__device__ __forceinline__ unsigned short f2b(float f){
  __bf16 h = (__bf16)f;                 // native v_cvt, RNE
  return __builtin_bit_cast(unsigned short, h);
}

// Barrier WITHOUT vmcnt drain: flush this wave's LDS ops, rendezvous, fence
// the compiler. Outstanding global loads (B-prefetch) stay in flight.
#define LBAR() do{ \
  asm volatile("s_waitcnt lgkmcnt(0)" ::: "memory"); \
  __builtin_amdgcn_s_barrier(); \
  asm volatile("" ::: "memory"); \
} while(0)

// wt[0..65536) = W1T[128][512]; wt[65536..98304) = W2T[256][128];
// wt[98304..163840) = W3T[256][256]   (all bf16)
__global__ __launch_bounds__(256) void prep_weights(
    const float* __restrict__ W1, const float* __restrict__ W2,
    const float* __restrict__ W3, unsigned short* __restrict__ wt){
  int id = blockIdx.x * 256 + threadIdx.x;
  if (id < 65536){
    int r = id >> 9, c = id & 511;
    wt[id] = f2b(W1[c * 128 + r]);
  } else if (id < 98304){
    int t = id - 65536; int r = t >> 7, c = t & 127;
    wt[id] = f2b(W2[c * 256 + r]);
  } else if (id < 163840){
    int t = id - 98304; int r = t >> 8, c = t & 255;
    wt[id] = f2b(W3[c * 256 + r]);
  }
}

// Rank-11 collapse of the S-half of GEMM1. coef[comb][12][128] f32.
__global__ __launch_bounds__(128) void prep_coef(
    const float* __restrict__ pts0, const float* __restrict__ pts1,
    const int* __restrict__ anc_i, const int* __restrict__ anc_j,
    const float* __restrict__ W1, float* __restrict__ coef){
  const int comb = blockIdx.x;          // 0..15
  const int strm = comb >> 3, n = comb & 7;
  const int col  = threadIdx.x;         // 0..127
  __shared__ float4 anc[64];
  const float* pts  = strm ? pts1 : pts0;
  const int*   anci = strm ? anc_j : anc_i;
  if (col < 64){
    int ai = anci[n * KANC + col];
    const float* ap = pts + ((size_t)n * LPTS + ai) * 3;
    anc[col] = make_float4(ap[0], ap[1], ap[2], 0.f);
  }
  __syncthreads();
  float SX=0,CX=0,SY=0,CY=0,SZ=0,CZ=0,SD=0,ADx=0,ADy=0,ADz=0,CD2=0;
  float SAx=0,SAy=0,SAz=0,SA2=0;
  for (int k = 0; k < KANC; ++k){
    float4 a = anc[k];
    float ak2 = a.x*a.x + a.y*a.y + a.z*a.z;
    float wx = W1[(256 + k) * 128 + col];
    float wy = W1[(320 + k) * 128 + col];
    float wz = W1[(384 + k) * 128 + col];
    float wd = W1[(448 + k) * 128 + col];
    SX += wx; CX += a.x * wx;
    SY += wy; CY += a.y * wy;
    SZ += wz; CZ += a.z * wz;
    SD += wd; ADx += a.x * wd; ADy += a.y * wd; ADz += a.z * wd;
    CD2 += ak2 * wd;
    SAx += a.x; SAy += a.y; SAz += a.z; SA2 += ak2;
  }
  float* cf = coef + (size_t)comb * 12 * 128;
  cf[ 0*128+col]=SX;  cf[ 1*128+col]=CX;  cf[ 2*128+col]=SY;  cf[ 3*128+col]=CY;
  cf[ 4*128+col]=SZ;  cf[ 5*128+col]=CZ;  cf[ 6*128+col]=SD;  cf[ 7*128+col]=ADx;
  cf[ 8*128+col]=ADy; cf[ 9*128+col]=ADz; cf[10*128+col]=CD2;
  if (col == 0) cf[11*128+0] = SAx;
  if (col == 1) cf[11*128+1] = SAy;
  if (col == 2) cf[11*128+2] = SAz;
  if (col == 3) cf[11*128+3] = SA2;
}

// TM=64, 512 threads (8 waves, GEMMs 1M x 8N). LDS 51 KiB.
__global__ __launch_bounds__(512, 4) void fused(
    const float* __restrict__ feat0, const float* __restrict__ feat1,
    const float* __restrict__ pts0, const float* __restrict__ pts1,
    const int* __restrict__ anc_i, const int* __restrict__ anc_j,
    const float* __restrict__ b1, const float* __restrict__ b2,
    const float* __restrict__ b3, const unsigned short* __restrict__ wt,
    const float* __restrict__ coef, float* __restrict__ out)
{
  __shared__ unsigned short xs[TM * 256];     // 32 KiB: feat tile [64][256]
  __shared__ unsigned short h1s[TM * H1DIM];  // 16 KiB
  __shared__ float scal[TM][12];              // 3 KiB: per-point u_j
  unsigned short* h2s = xs;                   // aliases xs (feat dead post-G1)
  float4* anc4 = (float4*)h1s;                // stride-9 padded, dead pre-h1s

  const int tid  = threadIdx.x;
  const int wg   = blockIdx.x;
  const int strm = wg >> 11;
  const int n    = (wg >> 8) & 7;
  const int l0   = (wg & 255) * TM;

  const float* feat = strm ? feat1 : feat0;
  const float* pts  = strm ? pts1 : pts0;
  const int*   anci = strm ? anc_j : anc_i;
  const float* cf   = coef + (size_t)((strm << 3) | n) * 12 * 128;

  const int lane = tid & 63;
  const int w    = tid >> 6;
  const int lr   = lane & 15;
  const int lg   = lane >> 4;
  const int col1 = w * 16 + lr;               // G1 column
  const int col0 = w * 32;                    // G2/G3 column base
  const unsigned short* wrow1 = wt + col1 * DIN;
  const unsigned short* w2t = wt + 65536;
  const unsigned short* w3t = wt + 98304;

  // ---- top-of-kernel prefetches: survive LBAR barriers ----
  bf16x8 g1b = *(const bf16x8*)&wrow1[lg * 8];
  bf16x8 g2b0 = *(const bf16x8*)&w2t[(col0      + lr) * H1DIM + lg * 8];
  bf16x8 g2b1 = *(const bf16x8*)&w2t[(col0 + 16 + lr) * H1DIM + lg * 8];
  bf16x8 g3b0 = *(const bf16x8*)&w3t[(col0      + lr) * H2DIM + lg * 8];
  bf16x8 g3b1 = *(const bf16x8*)&w3t[(col0 + 16 + lr) * H2DIM + lg * 8];

  // hoisted loads (latency hides under Phase A)
  const float* pp = pts + ((size_t)n * LPTS + l0 + (tid >> 3)) * 3;
  float px = pp[0], py = pp[1], pz = pp[2];
  float SAx = cf[11*128+0], SAy = cf[11*128+1], SAz = cf[11*128+2], SA2 = cf[11*128+3];

  // anchors -> LDS (stride-9 padded float4: conflict-free)
  if (tid < KANC){
    int ai = anci[n * KANC + tid];
    const float* ap = pts + ((size_t)n * LPTS + ai) * 3;
    anc4[tid + (tid >> 3)] = make_float4(ap[0], ap[1], ap[2], 0.f);
  }

  // ---- Phase A: feat tile -> xs[64][256] bf16 (coalesced, swizzled)
  {
    const float4* fb = (const float4*)(feat + ((size_t)n * LPTS + l0) * CDIM);
    #pragma unroll
    for (int it = 0; it < 8; ++it){
      int flat = it * 512 + tid;          // 4096 float4, 16B/lane coalesced
      int r = flat >> 6, c4 = flat & 63;
      float4 v = fb[flat];
      int e = (r * 256 + c4 * 4) ^ ((r & 7) << 3);
      u16x4 pk = { f2b(v.x), f2b(v.y), f2b(v.z), f2b(v.w) };
      *(u16x4*)&xs[e] = pk;
    }
  }
  LBAR();                                 // bar1: anchors + xs ready

  // ---- Phase B: L1 denominators + per-point scalars -> scal[64][12]
  {
    const int l   = tid >> 3;             // 0..63
    const int sub = tid & 7;
    float s0 = 0.f, s1 = 0.f, s2 = 0.f;
    #pragma unroll
    for (int i = 0; i < 8; ++i){
      float4 a = anc4[sub * 9 + i];
      s0 += fabsf(px - a.x); s1 += fabsf(py - a.y); s2 += fabsf(pz - a.z);
    }
    #pragma unroll
    for (int m = 1; m <= 4; m <<= 1){
      s0 += __shfl_xor(s0, m, 64);
      s1 += __shfl_xor(s1, m, 64);
      s2 += __shfl_xor(s2, m, 64);
    }
    float pp2 = px*px + py*py + pz*pz;
    float s3 = 64.f * pp2 - 2.f * (px*SAx + py*SAy + pz*SAz) + SA2;
    float i0 = 1.f/s0, i1 = 1.f/s1, i2 = 1.f/s2, i3 = 1.f/s3;
    float u;
    switch (sub){
      case 0: u = i0 * px;       break;
      case 1: u = -i0;           break;
      case 2: u = i1 * py;       break;
      case 3: u = -i1;           break;
      case 4: u = i2 * pz;       break;
      case 5: u = -i2;           break;
      case 6: u = i3 * pp2;      break;
      default: u = -2.f*i3*px;   break;
    }
    scal[l][sub] = u;
    if (sub < 3){
      float u2 = (sub == 0) ? -2.f*i3*py : (sub == 1) ? -2.f*i3*pz : i3;
      scal[l][8 + sub] = u2;
    }
  }
  LBAR();                                 // bar2: scal ready

  // ---- GEMM1: feat-part MFMA (K=256) + rank-11 S-part -> relu -> h1s
  {
    f32x4 acc[4] = {};
    float cc[11];
    #pragma unroll
    for (int j = 0; j < 11; ++j) cc[j] = cf[j * 128 + col1];
    #pragma unroll 4
    for (int kk = 0; kk < 8; ++kk){
      int kb = kk * 32 + lg * 8;
      bf16x8 b = (kk == 0) ? g1b : *(const bf16x8*)&wrow1[kb];
      #pragma unroll
      for (int m = 0; m < 4; ++m){
        int row = m * 16 + lr;
        bf16x8 a = *(const bf16x8*)&xs[(row * 256 + kb) ^ ((row & 7) << 3)];
        acc[m] = __builtin_amdgcn_mfma_f32_16x16x32_bf16(a, b, acc[m], 0, 0, 0);
      }
    }
    float bias = b1[col1];
    #pragma unroll
    for (int m = 0; m < 4; ++m){
      #pragma unroll
      for (int r = 0; r < 4; ++r){
        int row = m * 16 + lg * 4 + r;
        f32x4 ua = *(const f32x4*)&scal[row][0];
        f32x4 ub = *(const f32x4*)&scal[row][4];
        f32x4 uc = *(const f32x4*)&scal[row][8];
        float s = acc[m][r] + bias;
        s += ua[0]*cc[0] + ua[1]*cc[1] + ua[2]*cc[2] + ua[3]*cc[3];
        s += ub[0]*cc[4] + ub[1]*cc[5] + ub[2]*cc[6] + ub[3]*cc[7];
        s += uc[0]*cc[8] + uc[1]*cc[9] + uc[2]*cc[10];
        float v = fmaxf(s, 0.f);
        h1s[(row * H1DIM + col1) ^ ((row & 7) << 3)] = f2b(v);
      }
    }
  }
  LBAR();                                 // bar3: h1s ready, xs reads retired

  // ---- GEMM2: h1s[64,128] @ W2 -> relu -> h2s[64,256] (aliases xs)
  {
    f32x4 acc[4][2] = {};
    #pragma unroll
    for (int kk = 0; kk < 4; ++kk){
      int kb = kk * 32 + lg * 8;
      bf16x8 bf0 = (kk == 0) ? g2b0 : *(const bf16x8*)&w2t[(col0 + lr) * H1DIM + kb];
      bf16x8 bf1 = (kk == 0) ? g2b1 : *(const bf16x8*)&w2t[(col0 + 16 + lr) * H1DIM + kb];
      #pragma unroll
      for (int m = 0; m < 4; ++m){
        int row = m * 16 + lr;
        bf16x8 a = *(const bf16x8*)&h1s[(row * H1DIM + kb) ^ ((row & 7) << 3)];
        acc[m][0] = __builtin_amdgcn_mfma_f32_16x16x32_bf16(a, bf0, acc[m][0], 0, 0, 0);
        acc[m][1] = __builtin_amdgcn_mfma_f32_16x16x32_bf16(a, bf1, acc[m][1], 0, 0, 0);
      }
    }
    #pragma unroll
    for (int nt = 0; nt < 2; ++nt){
      int col = col0 + nt * 16 + lr;
      float bias = b2[col];
      #pragma unroll
      for (int m = 0; m < 4; ++m){
        #pragma unroll
        for (int r = 0; r < 4; ++r){
          int row = m * 16 + lg * 4 + r;
          float v = fmaxf(acc[m][nt][r] + bias, 0.f);
          h2s[(row * H2DIM + col) ^ ((row & 7) << 3)] = f2b(v);
        }
      }
    }
  }
  LBAR();                                 // bar4: h2s ready

  // ---- GEMM3: h2s[64,256] @ W3 -> + b3 -> out (f32)
  {
    f32x4 acc[4][2] = {};
    #pragma unroll 4
    for (int kk = 0; kk < 8; ++kk){
      int kb = kk * 32 + lg * 8;
      bf16x8 bf0 = (kk == 0) ? g3b0 : *(const bf16x8*)&w3t[(col0 + lr) * H2DIM + kb];
      bf16x8 bf1 = (kk == 0) ? g3b1 : *(const bf16x8*)&w3t[(col0 + 16 + lr) * H2DIM + kb];
      #pragma unroll
      for (int m = 0; m < 4; ++m){
        int row = m * 16 + lr;
        bf16x8 a = *(const bf16x8*)&h2s[(row * H2DIM + kb) ^ ((row & 7) << 3)];
        acc[m][0] = __builtin_amdgcn_mfma_f32_16x16x32_bf16(a, bf0, acc[m][0], 0, 0, 0);
        acc[m][1] = __builtin_amdgcn_mfma_f32_16x16x32_bf16(a, bf1, acc[m][1], 0, 0, 0);
      }
    }
    float* ob = out + (((size_t)strm * NBATCH + n) * LPTS + l0) * CDIM;
    #pragma unroll
    for (int nt = 0; nt < 2; ++nt){
      int col = col0 + nt * 16 + lr;
      float bias = b3[col];
      #pragma unroll
      for (int m = 0; m < 4; ++m){
        #pragma unroll
        for (int r = 0; r < 4; ++r){
          int row = m * 16 + lg * 4 + r;
          ob[(size_t)row * CDIM + col] = acc[m][nt][r] + bias;
        }
      }
    }
  }
}

extern "C" void kernel_launch(void* const* d_in, const int* in_sizes, int n_in,
                              void* d_out, int out_size, void* d_ws, size_t ws_size,
                              hipStream_t stream){
  const float* feat0 = (const float*)d_in[0];
  const float* feat1 = (const float*)d_in[1];
  const float* pts0  = (const float*)d_in[2];
  const float* pts1  = (const float*)d_in[3];
  const int*   anci  = (const int*)d_in[4];
  const int*   ancj  = (const int*)d_in[5];
  const float* W1    = (const float*)d_in[6];
  const float* b1    = (const float*)d_in[7];
  const float* W2    = (const float*)d_in[8];
  const float* b2    = (const float*)d_in[9];
  const float* W3    = (const float*)d_in[10];
  const float* b3    = (const float*)d_in[11];
  unsigned short* wt = (unsigned short*)d_ws;
  float* coef = (float*)((char*)d_ws + 163840 * sizeof(unsigned short));
  float* out = (float*)d_out;

  prep_weights<<<640, 256, 0, stream>>>(W1, W2, W3, wt);
  prep_coef<<<16, 128, 0, stream>>>(pts0, pts1, anci, ancj, W1, coef);
  fused<<<4096, 512, 0, stream>>>(feat0, feat1, pts0, pts1, anci, ancj,
                                  b1, b2, b3, wt, coef, out);
}